// Round 8
// baseline (1005.577 us; speedup 1.0000x reference)
//
#include <hip/hip_runtime.h>

static constexpr int N_NODES = 50000;
static constexpr int N_EDGES = 1600000;
static constexpr int CIN = 32;
static constexpr int HID = 64;
static constexpr int NTB = N_NODES / 16;          // 3125 transform blocks
static constexpr int NBUCK = (N_NODES + 31) / 32; // 1563 buckets of 32 nodes
static constexpr int EPB = N_EDGES / 256;         // 6250 edges per build block

__device__ __forceinline__ unsigned short f2bf(float f) {
    unsigned int u = __float_as_uint(f);
    u = (u + 0x7fffu + ((u >> 16) & 1u)) >> 16;   // RNE
    return (unsigned short)u;
}
__device__ __forceinline__ float bfhi(unsigned int u) { return __uint_as_float(u & 0xffff0000u); }
__device__ __forceinline__ float bflo(unsigned int u) { return __uint_as_float(u << 16); }

// ---------------- bucket build ----------------
// buckets of 32 consecutive dst nodes; entry = (src<<5)|loc

__global__ void __launch_bounds__(256)
histB_kernel(const int* __restrict__ ei, int* __restrict__ part) {
    __shared__ int hist[NBUCK];
    for (int i = threadIdx.x; i < NBUCK; i += 256) hist[i] = 0;
    __syncthreads();
    const int base = blockIdx.x * EPB;
    for (int i = threadIdx.x; i < EPB; i += 256)
        atomicAdd(&hist[ei[N_EDGES + base + i] >> 5], 1);
    __syncthreads();
    for (int i = threadIdx.x; i < NBUCK; i += 256)
        part[i * 256 + blockIdx.x] = hist[i];
}

// per bucket: exclusive scan over the 256 block counts
__global__ void __launch_bounds__(256)
scanA_kernel(int* __restrict__ part, int* __restrict__ btot) {
    __shared__ int s[256];
    const int t = threadIdx.x;
    const int v = part[blockIdx.x * 256 + t];
    s[t] = v;
    __syncthreads();
    for (int st = 1; st < 256; st <<= 1) {
        int u = (t >= st) ? s[t - st] : 0;
        __syncthreads();
        s[t] += u;
        __syncthreads();
    }
    part[blockIdx.x * 256 + t] = s[t] - v;
    if (t == 255) btot[blockIdx.x] = s[255];
}

// single block: exclusive scan of btot[NBUCK] -> bstart[NBUCK+1]
__global__ void __launch_bounds__(1024)
scanB_kernel(const int* __restrict__ btot, int* __restrict__ bstart) {
    __shared__ int pairs[1024];
    __shared__ int v0s[1024];
    const int t = threadIdx.x;
    const int i0 = 2 * t, i1 = 2 * t + 1;
    const int v0 = (i0 < NBUCK) ? btot[i0] : 0;
    const int v1 = (i1 < NBUCK) ? btot[i1] : 0;
    v0s[t] = v0;
    const int p = v0 + v1;
    pairs[t] = p;
    __syncthreads();
    for (int st = 1; st < 1024; st <<= 1) {
        int u = (t >= st) ? pairs[t - st] : 0;
        __syncthreads();
        pairs[t] += u;
        __syncthreads();
    }
    const int base = pairs[t] - p;
    if (i0 < NBUCK) bstart[i0] = base;
    if (i1 < NBUCK) bstart[i1] = base + v0s[t];
    if (t == 1023) bstart[NBUCK] = pairs[1023];   // == N_EDGES
}

__global__ void __launch_bounds__(256)
scatterB_kernel(const int* __restrict__ ei, const int* __restrict__ part,
                const int* __restrict__ bstart, unsigned* __restrict__ bentry) {
    __shared__ int cur[NBUCK];
    for (int i = threadIdx.x; i < NBUCK; i += 256)
        cur[i] = bstart[i] + part[i * 256 + blockIdx.x];
    __syncthreads();
    const int base = blockIdx.x * EPB;
    for (int i = threadIdx.x; i < EPB; i += 256) {
        const int s = ei[base + i];
        const int d = ei[N_EDGES + base + i];
        const int pos = atomicAdd(&cur[d >> 5], 1);
        bentry[pos] = ((unsigned)s << 5) | (unsigned)(d & 31);
    }
}

// ---------------- agg0: LDS-accumulated mean of x rows -> mean0b (bf16) ----
// block per bucket; 32 groups x 8 lanes; group streams entries 4-deep.
__global__ void __launch_bounds__(256)
agg0L_kernel(const float* __restrict__ x, const int* __restrict__ bstart,
             const unsigned* __restrict__ bentry, unsigned short* __restrict__ mean0b) {
    __shared__ float acc[32 * 33];
    __shared__ float sdeg[32];
    for (int i = threadIdx.x; i < 32 * 33; i += 256) acc[i] = 0.f;
    if (threadIdx.x < 32) sdeg[threadIdx.x] = 0.f;
    __syncthreads();
    const int bkt = blockIdx.x;
    const int s0 = bstart[bkt], s1 = bstart[bkt + 1];
    const int g = threadIdx.x >> 3, cg = threadIdx.x & 7;
    for (int e = s0 + g; e < s1; e += 128) {
        unsigned ent[4];
        bool val[4];
#pragma unroll
        for (int k = 0; k < 4; ++k) {
            const int ee = e + k * 32;
            val[k] = ee < s1;
            ent[k] = val[k] ? bentry[ee] : 0u;
        }
        float4 v[4];
#pragma unroll
        for (int k = 0; k < 4; ++k)
            if (val[k])
                v[k] = *reinterpret_cast<const float4*>(x + (size_t)(ent[k] >> 5) * CIN + cg * 4);
#pragma unroll
        for (int k = 0; k < 4; ++k)
            if (val[k]) {
                float* ar = acc + (ent[k] & 31) * 33 + cg * 4;
                atomicAdd(ar + 0, v[k].x);
                atomicAdd(ar + 1, v[k].y);
                atomicAdd(ar + 2, v[k].z);
                atomicAdd(ar + 3, v[k].w);
                if (cg == 0) atomicAdd(&sdeg[ent[k] & 31], 1.0f);
            }
    }
    __syncthreads();
    const int nb = bkt * 32;
    for (int i = threadIdx.x; i < 32 * 16; i += 256) {
        const int n = i >> 4, cp = i & 15;
        const int gn = nb + n;
        if (gn < N_NODES) {
            const float inv = 1.0f / fmaxf(sdeg[n], 1.0f);
            reinterpret_cast<unsigned*>(mean0b)[(size_t)gn * 16 + cp] =
                (unsigned)f2bf(acc[n * 33 + 2 * cp] * inv) |
                ((unsigned)f2bf(acc[n * 33 + 2 * cp + 1] * inv) << 16);
        }
    }
}

// ---------------- agg1: LDS-accumulated mean of h rows (bf16) -> mean1f ----
__global__ void __launch_bounds__(256)
agg1L_kernel(const unsigned short* __restrict__ hb, const int* __restrict__ bstart,
             const unsigned* __restrict__ bentry, float* __restrict__ mean1f) {
    __shared__ float acc[32 * 65];
    __shared__ float sdeg[32];
    for (int i = threadIdx.x; i < 32 * 65; i += 256) acc[i] = 0.f;
    if (threadIdx.x < 32) sdeg[threadIdx.x] = 0.f;
    __syncthreads();
    const int bkt = blockIdx.x;
    const int s0 = bstart[bkt], s1 = bstart[bkt + 1];
    const int g = threadIdx.x >> 3, cg = threadIdx.x & 7;
    for (int e = s0 + g; e < s1; e += 128) {
        unsigned ent[4];
        bool val[4];
#pragma unroll
        for (int k = 0; k < 4; ++k) {
            const int ee = e + k * 32;
            val[k] = ee < s1;
            ent[k] = val[k] ? bentry[ee] : 0u;
        }
        uint4 u[4];
#pragma unroll
        for (int k = 0; k < 4; ++k)
            if (val[k])
                u[k] = *reinterpret_cast<const uint4*>(hb + (size_t)(ent[k] >> 5) * HID + cg * 8);
#pragma unroll
        for (int k = 0; k < 4; ++k)
            if (val[k]) {
                float* ar = acc + (ent[k] & 31) * 65 + cg * 8;
                atomicAdd(ar + 0, bflo(u[k].x));
                atomicAdd(ar + 1, bfhi(u[k].x));
                atomicAdd(ar + 2, bflo(u[k].y));
                atomicAdd(ar + 3, bfhi(u[k].y));
                atomicAdd(ar + 4, bflo(u[k].z));
                atomicAdd(ar + 5, bfhi(u[k].z));
                atomicAdd(ar + 6, bflo(u[k].w));
                atomicAdd(ar + 7, bfhi(u[k].w));
                if (cg == 0) atomicAdd(&sdeg[ent[k] & 31], 1.0f);
            }
    }
    __syncthreads();
    const int nb = bkt * 32;
    for (int i = threadIdx.x; i < 32 * 64; i += 256) {
        const int n = i >> 6, ch = i & 63;
        const int gn = nb + n;
        if (gn < N_NODES)
            mean1f[(size_t)gn * 64 + ch] = acc[n * 65 + ch] / fmaxf(sdeg[n], 1.0f);
    }
}

// ---------------- transform 0 (R7-proven) ----------------
__global__ void __launch_bounds__(256)
transform0_kernel(const float* __restrict__ x,
                  const unsigned short* __restrict__ mean0b,
                  const float* __restrict__ Wl0, const float* __restrict__ Wr0,
                  const float* __restrict__ b0,
                  unsigned short* __restrict__ hb) {
    __shared__ float sWl[CIN * HID];
    __shared__ float sWr[CIN * HID];
    __shared__ float sMin[16 * CIN];
    __shared__ float sXin[16 * CIN];
    const int t = threadIdx.x;
    const int blk = blockIdx.x;
    reinterpret_cast<float4*>(sWl)[t]       = reinterpret_cast<const float4*>(Wl0)[t];
    reinterpret_cast<float4*>(sWl)[t + 256] = reinterpret_cast<const float4*>(Wl0)[t + 256];
    reinterpret_cast<float4*>(sWr)[t]       = reinterpret_cast<const float4*>(Wr0)[t];
    reinterpret_cast<float4*>(sWr)[t + 256] = reinterpret_cast<const float4*>(Wr0)[t + 256];
    {
        const unsigned u = reinterpret_cast<const unsigned*>(mean0b)[blk * 256 + t];
        sMin[2 * t]     = bflo(u);
        sMin[2 * t + 1] = bfhi(u);
    }
    if (t < 128)
        reinterpret_cast<float4*>(sXin)[t] =
            reinterpret_cast<const float4*>(x + (size_t)blk * 16 * CIN)[t];
    __syncthreads();

    const int n = t >> 4, cg = t & 15;
    const float4 bv = reinterpret_cast<const float4*>(b0)[cg];
    float a[4] = {bv.x, bv.y, bv.z, bv.w};
#pragma unroll
    for (int k = 0; k < CIN; ++k) {
        const float m  = sMin[n * CIN + k];
        const float xx = sXin[n * CIN + k];
        const float4 wl = reinterpret_cast<const float4*>(sWl + k * HID)[cg];
        const float4 wr = reinterpret_cast<const float4*>(sWr + k * HID)[cg];
        a[0] = fmaf(m, wl.x, fmaf(xx, wr.x, a[0]));
        a[1] = fmaf(m, wl.y, fmaf(xx, wr.y, a[1]));
        a[2] = fmaf(m, wl.z, fmaf(xx, wr.z, a[2]));
        a[3] = fmaf(m, wl.w, fmaf(xx, wr.w, a[3]));
    }
    float ss = a[0] * a[0] + a[1] * a[1] + a[2] * a[2] + a[3] * a[3];
    ss += __shfl_xor(ss, 1);
    ss += __shfl_xor(ss, 2);
    ss += __shfl_xor(ss, 4);
    ss += __shfl_xor(ss, 8);
    const float sc = 1.0f / fmaxf(sqrtf(ss), 1e-12f);
    uint2 o;
    o.x = (unsigned)f2bf(fmaxf(a[0] * sc, 0.f)) | ((unsigned)f2bf(fmaxf(a[1] * sc, 0.f)) << 16);
    o.y = (unsigned)f2bf(fmaxf(a[2] * sc, 0.f)) | ((unsigned)f2bf(fmaxf(a[3] * sc, 0.f)) << 16);
    reinterpret_cast<uint2*>(hb)[(size_t)(blk * 16 + n) * 16 + cg] = o;
}

// ---------------- transform 1 (R7-proven) ----------------
__global__ void __launch_bounds__(256)
transform1_kernel(const unsigned short* __restrict__ hb,
                  const float* __restrict__ mean1f,
                  const float* __restrict__ Wl1, const float* __restrict__ Wr1,
                  const float* __restrict__ b1,
                  const float* __restrict__ Wc1, const float* __restrict__ bc1,
                  const float* __restrict__ Wc2, const float* __restrict__ bc2,
                  float* __restrict__ out) {
    __shared__ float sWl[HID * HID];
    __shared__ float sWr[HID * HID];
    __shared__ float sWc[HID * 32];
    __shared__ float sMin[16 * HID];
    __shared__ float sHin[16 * HID];
    __shared__ float sV[16 * HID];
    const int t = threadIdx.x;
    const int blk = blockIdx.x;
#pragma unroll
    for (int i = 0; i < 4; ++i) {
        reinterpret_cast<float4*>(sWl)[t + 256 * i] = reinterpret_cast<const float4*>(Wl1)[t + 256 * i];
        reinterpret_cast<float4*>(sWr)[t + 256 * i] = reinterpret_cast<const float4*>(Wr1)[t + 256 * i];
    }
#pragma unroll
    for (int i = 0; i < 2; ++i)
        reinterpret_cast<float4*>(sWc)[t + 256 * i] = reinterpret_cast<const float4*>(Wc1)[t + 256 * i];
    reinterpret_cast<float4*>(sMin)[t] =
        reinterpret_cast<const float4*>(mean1f + (size_t)blk * 16 * HID)[t];
    {
        const uint2 hu = reinterpret_cast<const uint2*>(hb)[(size_t)blk * 256 + t];
        sHin[4 * t]     = bflo(hu.x);
        sHin[4 * t + 1] = bfhi(hu.x);
        sHin[4 * t + 2] = bflo(hu.y);
        sHin[4 * t + 3] = bfhi(hu.y);
    }
    __syncthreads();

    const int n = t >> 4, cg = t & 15;
    const float4 bv = reinterpret_cast<const float4*>(b1)[cg];
    float a[4] = {bv.x, bv.y, bv.z, bv.w};
#pragma unroll
    for (int k = 0; k < HID; ++k) {
        const float m  = sMin[n * HID + k];
        const float hh = sHin[n * HID + k];
        const float4 wl = reinterpret_cast<const float4*>(sWl + k * HID)[cg];
        const float4 wr = reinterpret_cast<const float4*>(sWr + k * HID)[cg];
        a[0] = fmaf(m, wl.x, fmaf(hh, wr.x, a[0]));
        a[1] = fmaf(m, wl.y, fmaf(hh, wr.y, a[1]));
        a[2] = fmaf(m, wl.z, fmaf(hh, wr.z, a[2]));
        a[3] = fmaf(m, wl.w, fmaf(hh, wr.w, a[3]));
    }
    float ss = a[0] * a[0] + a[1] * a[1] + a[2] * a[2] + a[3] * a[3];
    ss += __shfl_xor(ss, 1);
    ss += __shfl_xor(ss, 2);
    ss += __shfl_xor(ss, 4);
    ss += __shfl_xor(ss, 8);
    const float sc = 1.0f / fmaxf(sqrtf(ss), 1e-12f);
    sV[n * HID + 4 * cg + 0] = a[0] * sc;
    sV[n * HID + 4 * cg + 1] = a[1] * sc;
    sV[n * HID + 4 * cg + 2] = a[2] * sc;
    sV[n * HID + 4 * cg + 3] = a[3] * sc;
    __syncthreads();

    float c1a = bc1[cg], c1b = bc1[cg + 16];
#pragma unroll
    for (int k = 0; k < HID; ++k) {
        const float vv = sV[n * HID + k];
        c1a = fmaf(vv, sWc[k * 32 + cg], c1a);
        c1b = fmaf(vv, sWc[k * 32 + cg + 16], c1b);
    }
    float pp = fmaxf(c1a, 0.f) * Wc2[cg] + fmaxf(c1b, 0.f) * Wc2[cg + 16];
    pp += __shfl_xor(pp, 1);
    pp += __shfl_xor(pp, 2);
    pp += __shfl_xor(pp, 4);
    pp += __shfl_xor(pp, 8);
    if (cg == 0) out[blk * 16 + n] = pp + bc2[0];
}

extern "C" void kernel_launch(void* const* d_in, const int* in_sizes, int n_in,
                              void* d_out, int out_size, void* d_ws, size_t ws_size,
                              hipStream_t stream) {
    const float* x   = (const float*)d_in[0];
    const int*   ei  = (const int*)d_in[1];
    const float* Wl0 = (const float*)d_in[2];
    const float* b0  = (const float*)d_in[3];
    const float* Wr0 = (const float*)d_in[4];
    const float* Wl1 = (const float*)d_in[5];
    const float* b1  = (const float*)d_in[6];
    const float* Wr1 = (const float*)d_in[7];
    const float* Wc1 = (const float*)d_in[8];
    const float* bc1 = (const float*)d_in[9];
    const float* Wc2 = (const float*)d_in[10];
    const float* bc2 = (const float*)d_in[11];
    float* out = (float*)d_out;

    // ws layout (float offsets). Liveness-packed: mean1f overlaps part/mean0b/btot
    // (all dead before agg1L writes mean1f). Total 25.6 MB.
    float* W = (float*)d_ws;
    int*            part   = (int*)W;                           // [0, 400128)   dead after scatterB
    unsigned short* mean0b = (unsigned short*)(W + 400128);     // [400128, 1200128) dead after t0
    int*            btot   = (int*)(W + 1200128);               // [1200128, ~1201696) dead after scanB
    float*          mean1f = W;                                 // [0, 3200000)  written agg1L
    int*            bstart = (int*)(W + 3200000);               // [3200000, 3201600)
    unsigned*       bentry = (unsigned*)(W + 3201600);          // [3201600, 4801600)
    unsigned short* hb     = (unsigned short*)(W + 4801600);    // [4801600, 6401600)

    const int T = 256;
    histB_kernel<<<256, T, 0, stream>>>(ei, part);
    scanA_kernel<<<NBUCK, T, 0, stream>>>(part, btot);
    scanB_kernel<<<1, 1024, 0, stream>>>(btot, bstart);
    scatterB_kernel<<<256, T, 0, stream>>>(ei, part, bstart, bentry);

    agg0L_kernel<<<NBUCK, T, 0, stream>>>(x, bstart, bentry, mean0b);
    transform0_kernel<<<NTB, T, 0, stream>>>(x, mean0b, Wl0, Wr0, b0, hb);
    agg1L_kernel<<<NBUCK, T, 0, stream>>>(hb, bstart, bentry, mean1f);
    transform1_kernel<<<NTB, T, 0, stream>>>(hb, mean1f, Wl1, Wr1, b1,
                                             Wc1, bc1, Wc2, bc2, out);
}

// Round 9
// 158.721 us; speedup vs baseline: 6.3355x; 6.3355x over previous
//
#include <hip/hip_runtime.h>

static constexpr int N_NODES = 50000;
static constexpr int N_EDGES = 1600000;
static constexpr int CIN = 32;
static constexpr int HID = 64;
static constexpr int NTB = N_NODES / 16;          // 3125 transform blocks
static constexpr int NBUCK = (N_NODES + 31) / 32; // 1563 buckets of 32 nodes
static constexpr int NB_BLD = 128;                // build blocks
static constexpr int EPB2 = N_EDGES / NB_BLD;     // 12500 edges per build block

__device__ __forceinline__ unsigned short f2bf(float f) {
    unsigned int u = __float_as_uint(f);
    u = (u + 0x7fffu + ((u >> 16) & 1u)) >> 16;   // RNE
    return (unsigned short)u;
}
__device__ __forceinline__ float bfhi(unsigned int u) { return __uint_as_float(u & 0xffff0000u); }
__device__ __forceinline__ float bflo(unsigned int u) { return __uint_as_float(u << 16); }

// ---------------- build: LDS-cursor bucket sort + within-bucket node sort ----

__global__ void __launch_bounds__(256)
histB_kernel(const int* __restrict__ ei, int* __restrict__ part) {
    __shared__ int hist[NBUCK];
    for (int i = threadIdx.x; i < NBUCK; i += 256) hist[i] = 0;
    __syncthreads();
    const int base = blockIdx.x * EPB2;
    const int t = threadIdx.x;
    for (int i0 = 0; i0 < EPB2; i0 += 1024) {
        int d[4];
#pragma unroll
        for (int k = 0; k < 4; ++k) {
            const int i = i0 + k * 256 + t;
            d[k] = (i < EPB2) ? ei[N_EDGES + base + i] : -1;
        }
#pragma unroll
        for (int k = 0; k < 4; ++k)
            if (d[k] >= 0) atomicAdd(&hist[d[k] >> 5], 1);
    }
    __syncthreads();
    for (int i = threadIdx.x; i < NBUCK; i += 256)
        part[i * NB_BLD + blockIdx.x] = hist[i];
}

// per bucket: exclusive scan over the 128 block counts
__global__ void __launch_bounds__(NB_BLD)
scanA_kernel(int* __restrict__ part, int* __restrict__ btot) {
    __shared__ int s[NB_BLD];
    const int t = threadIdx.x;
    const int v = part[blockIdx.x * NB_BLD + t];
    s[t] = v;
    __syncthreads();
    for (int st = 1; st < NB_BLD; st <<= 1) {
        int u = (t >= st) ? s[t - st] : 0;
        __syncthreads();
        s[t] += u;
        __syncthreads();
    }
    part[blockIdx.x * NB_BLD + t] = s[t] - v;
    if (t == NB_BLD - 1) btot[blockIdx.x] = s[NB_BLD - 1];
}

// single block: exclusive scan of btot[NBUCK] -> bstart[NBUCK+1]
__global__ void __launch_bounds__(1024)
scanB_kernel(const int* __restrict__ btot, int* __restrict__ bstart) {
    __shared__ int pairs[1024];
    __shared__ int v0s[1024];
    const int t = threadIdx.x;
    const int i0 = 2 * t, i1 = 2 * t + 1;
    const int v0 = (i0 < NBUCK) ? btot[i0] : 0;
    const int v1 = (i1 < NBUCK) ? btot[i1] : 0;
    v0s[t] = v0;
    const int p = v0 + v1;
    pairs[t] = p;
    __syncthreads();
    for (int st = 1; st < 1024; st <<= 1) {
        int u = (t >= st) ? pairs[t - st] : 0;
        __syncthreads();
        pairs[t] += u;
        __syncthreads();
    }
    const int base = pairs[t] - p;
    if (i0 < NBUCK) bstart[i0] = base;
    if (i1 < NBUCK) bstart[i1] = base + v0s[t];
    if (t == 1023) bstart[NBUCK] = pairs[1023];   // == N_EDGES
}

__global__ void __launch_bounds__(256)
scatterB_kernel(const int* __restrict__ ei, const int* __restrict__ part,
                const int* __restrict__ bstart, unsigned* __restrict__ bentry) {
    __shared__ int cur[NBUCK];
    for (int i = threadIdx.x; i < NBUCK; i += 256)
        cur[i] = bstart[i] + part[i * NB_BLD + blockIdx.x];
    __syncthreads();
    const int base = blockIdx.x * EPB2;
    const int t = threadIdx.x;
    for (int i0 = 0; i0 < EPB2; i0 += 1024) {
        int s[4], d[4];
#pragma unroll
        for (int k = 0; k < 4; ++k) {
            const int i = i0 + k * 256 + t;
            const bool val = i < EPB2;
            s[k] = val ? ei[base + i] : 0;
            d[k] = val ? ei[N_EDGES + base + i] : -1;
        }
#pragma unroll
        for (int k = 0; k < 4; ++k)
            if (d[k] >= 0) {
                const int pos = atomicAdd(&cur[d[k] >> 5], 1);
                bentry[pos] = ((unsigned)s[k] << 5) | (unsigned)(d[k] & 31);
            }
    }
}

// block per bucket: sort its entries to node order, emit sorted_src + off
__global__ void __launch_bounds__(256)
sortW_kernel(const unsigned* __restrict__ bentry, const int* __restrict__ bstart,
             int* __restrict__ sorted_src, int* __restrict__ off) {
    __shared__ int cnt[32];
    __shared__ int base[33];
    __shared__ int cur[32];
    const int b = blockIdx.x, t = threadIdx.x;
    const int s0 = bstart[b], s1 = bstart[b + 1];
    if (t < 32) cnt[t] = 0;
    __syncthreads();
    for (int i = s0 + t; i < s1; i += 256)
        atomicAdd(&cnt[bentry[i] & 31], 1);
    __syncthreads();
    if (t == 0) {
        int run = s0;
#pragma unroll
        for (int l = 0; l < 32; ++l) { base[l] = run; cur[l] = run; run += cnt[l]; }
        base[32] = run;
    }
    __syncthreads();
    if (t <= 32) {
        const int gn = b * 32 + t;
        if (gn <= N_NODES) off[gn] = base[t];
    }
    for (int i = s0 + t; i < s1; i += 256) {
        const unsigned e = bentry[i];
        const int pos = atomicAdd(&cur[e & 31], 1);
        sorted_src[pos] = (int)(e >> 5);
    }
}

// ---------------- agg0 (R7-proven): mean of neighbor x rows -> mean0b ------
__global__ void __launch_bounds__(256)
agg0_kernel(const float* __restrict__ x,
            const int* __restrict__ off, const int* __restrict__ src,
            unsigned short* __restrict__ mean0b) {
    const int node = blockIdx.x * 4 + (threadIdx.x >> 6);
    const int lane = threadIdx.x & 63;
    if (node >= N_NODES) return;
    const int e0 = off[node], e1 = off[node + 1];
    const int deg = e1 - e0;
    const int grp = lane >> 3, cg = lane & 7;

    float a[4] = {0, 0, 0, 0};
    for (int base = e0; base < e1; base += 64) {
        const int cnt = min(64, e1 - base);
        const int p = base + lane;
        const int sidx = (p < e1) ? src[p] : 0;
        const int nb = (cnt + 7) >> 3;
        float4 u[8];
#pragma unroll
        for (int t = 0; t < 8; ++t) u[t] = make_float4(0.f, 0.f, 0.f, 0.f);
#pragma unroll
        for (int t = 0; t < 8; ++t) {
            if (t < nb) {
                const int pos = (t << 3) | grp;
                const int s = __shfl(sidx, pos);
                if (pos < cnt)
                    u[t] = *reinterpret_cast<const float4*>(x + (size_t)s * CIN + cg * 4);
            }
        }
#pragma unroll
        for (int t = 0; t < 8; ++t) {
            a[0] += u[t].x; a[1] += u[t].y; a[2] += u[t].z; a[3] += u[t].w;
        }
    }
#pragma unroll
    for (int j = 0; j < 4; ++j) {
        a[j] += __shfl_xor(a[j], 8);
        a[j] += __shfl_xor(a[j], 16);
        a[j] += __shfl_xor(a[j], 32);
    }
    const float inv = 1.0f / fmaxf((float)deg, 1.0f);
    if (grp == 0) {
        uint2 o;
        o.x = (unsigned)f2bf(a[0] * inv) | ((unsigned)f2bf(a[1] * inv) << 16);
        o.y = (unsigned)f2bf(a[2] * inv) | ((unsigned)f2bf(a[3] * inv) << 16);
        reinterpret_cast<uint2*>(mean0b)[node * 8 + cg] = o;
    }
}

// ---------------- agg1 (R7-proven): mean of neighbor h rows -> mean1f ------
__global__ void __launch_bounds__(256)
agg1_kernel(const unsigned short* __restrict__ hb,
            const int* __restrict__ off, const int* __restrict__ src,
            float* __restrict__ mean1f) {
    const int node = blockIdx.x * 4 + (threadIdx.x >> 6);
    const int lane = threadIdx.x & 63;
    if (node >= N_NODES) return;
    const int e0 = off[node], e1 = off[node + 1];
    const int deg = e1 - e0;
    const int grp = lane >> 3, cg = lane & 7;

    float a[8] = {0, 0, 0, 0, 0, 0, 0, 0};
    for (int base = e0; base < e1; base += 64) {
        const int cnt = min(64, e1 - base);
        const int p = base + lane;
        const int sidx = (p < e1) ? src[p] : 0;
        const int nb = (cnt + 7) >> 3;
        uint4 u[8];
#pragma unroll
        for (int t = 0; t < 8; ++t) u[t] = make_uint4(0u, 0u, 0u, 0u);
#pragma unroll
        for (int t = 0; t < 8; ++t) {
            if (t < nb) {
                const int pos = (t << 3) | grp;
                const int s = __shfl(sidx, pos);
                if (pos < cnt)
                    u[t] = *reinterpret_cast<const uint4*>(hb + (size_t)s * HID + cg * 8);
            }
        }
#pragma unroll
        for (int t = 0; t < 8; ++t) {
            a[0] += bflo(u[t].x); a[1] += bfhi(u[t].x);
            a[2] += bflo(u[t].y); a[3] += bfhi(u[t].y);
            a[4] += bflo(u[t].z); a[5] += bfhi(u[t].z);
            a[6] += bflo(u[t].w); a[7] += bfhi(u[t].w);
        }
    }
#pragma unroll
    for (int j = 0; j < 8; ++j) {
        a[j] += __shfl_xor(a[j], 8);
        a[j] += __shfl_xor(a[j], 16);
        a[j] += __shfl_xor(a[j], 32);
    }
    const float inv = 1.0f / fmaxf((float)deg, 1.0f);
    if (grp == 0) {
        float4 o1 = make_float4(a[0] * inv, a[1] * inv, a[2] * inv, a[3] * inv);
        float4 o2 = make_float4(a[4] * inv, a[5] * inv, a[6] * inv, a[7] * inv);
        float4* dst = reinterpret_cast<float4*>(mean1f + (size_t)node * HID + cg * 8);
        dst[0] = o1; dst[1] = o2;
    }
}

// ---------------- transform 0 (R7-proven) ----------------
__global__ void __launch_bounds__(256)
transform0_kernel(const float* __restrict__ x,
                  const unsigned short* __restrict__ mean0b,
                  const float* __restrict__ Wl0, const float* __restrict__ Wr0,
                  const float* __restrict__ b0,
                  unsigned short* __restrict__ hb) {
    __shared__ float sWl[CIN * HID];
    __shared__ float sWr[CIN * HID];
    __shared__ float sMin[16 * CIN];
    __shared__ float sXin[16 * CIN];
    const int t = threadIdx.x;
    const int blk = blockIdx.x;
    reinterpret_cast<float4*>(sWl)[t]       = reinterpret_cast<const float4*>(Wl0)[t];
    reinterpret_cast<float4*>(sWl)[t + 256] = reinterpret_cast<const float4*>(Wl0)[t + 256];
    reinterpret_cast<float4*>(sWr)[t]       = reinterpret_cast<const float4*>(Wr0)[t];
    reinterpret_cast<float4*>(sWr)[t + 256] = reinterpret_cast<const float4*>(Wr0)[t + 256];
    {
        const unsigned u = reinterpret_cast<const unsigned*>(mean0b)[blk * 256 + t];
        sMin[2 * t]     = bflo(u);
        sMin[2 * t + 1] = bfhi(u);
    }
    if (t < 128)
        reinterpret_cast<float4*>(sXin)[t] =
            reinterpret_cast<const float4*>(x + (size_t)blk * 16 * CIN)[t];
    __syncthreads();

    const int n = t >> 4, cg = t & 15;
    const float4 bv = reinterpret_cast<const float4*>(b0)[cg];
    float a[4] = {bv.x, bv.y, bv.z, bv.w};
#pragma unroll
    for (int k = 0; k < CIN; ++k) {
        const float m  = sMin[n * CIN + k];
        const float xx = sXin[n * CIN + k];
        const float4 wl = reinterpret_cast<const float4*>(sWl + k * HID)[cg];
        const float4 wr = reinterpret_cast<const float4*>(sWr + k * HID)[cg];
        a[0] = fmaf(m, wl.x, fmaf(xx, wr.x, a[0]));
        a[1] = fmaf(m, wl.y, fmaf(xx, wr.y, a[1]));
        a[2] = fmaf(m, wl.z, fmaf(xx, wr.z, a[2]));
        a[3] = fmaf(m, wl.w, fmaf(xx, wr.w, a[3]));
    }
    float ss = a[0] * a[0] + a[1] * a[1] + a[2] * a[2] + a[3] * a[3];
    ss += __shfl_xor(ss, 1);
    ss += __shfl_xor(ss, 2);
    ss += __shfl_xor(ss, 4);
    ss += __shfl_xor(ss, 8);
    const float sc = 1.0f / fmaxf(sqrtf(ss), 1e-12f);
    uint2 o;
    o.x = (unsigned)f2bf(fmaxf(a[0] * sc, 0.f)) | ((unsigned)f2bf(fmaxf(a[1] * sc, 0.f)) << 16);
    o.y = (unsigned)f2bf(fmaxf(a[2] * sc, 0.f)) | ((unsigned)f2bf(fmaxf(a[3] * sc, 0.f)) << 16);
    reinterpret_cast<uint2*>(hb)[(size_t)(blk * 16 + n) * 16 + cg] = o;
}

// ---------------- transform 1 (R7-proven) ----------------
__global__ void __launch_bounds__(256)
transform1_kernel(const unsigned short* __restrict__ hb,
                  const float* __restrict__ mean1f,
                  const float* __restrict__ Wl1, const float* __restrict__ Wr1,
                  const float* __restrict__ b1,
                  const float* __restrict__ Wc1, const float* __restrict__ bc1,
                  const float* __restrict__ Wc2, const float* __restrict__ bc2,
                  float* __restrict__ out) {
    __shared__ float sWl[HID * HID];
    __shared__ float sWr[HID * HID];
    __shared__ float sWc[HID * 32];
    __shared__ float sMin[16 * HID];
    __shared__ float sHin[16 * HID];
    __shared__ float sV[16 * HID];
    const int t = threadIdx.x;
    const int blk = blockIdx.x;
#pragma unroll
    for (int i = 0; i < 4; ++i) {
        reinterpret_cast<float4*>(sWl)[t + 256 * i] = reinterpret_cast<const float4*>(Wl1)[t + 256 * i];
        reinterpret_cast<float4*>(sWr)[t + 256 * i] = reinterpret_cast<const float4*>(Wr1)[t + 256 * i];
    }
#pragma unroll
    for (int i = 0; i < 2; ++i)
        reinterpret_cast<float4*>(sWc)[t + 256 * i] = reinterpret_cast<const float4*>(Wc1)[t + 256 * i];
    reinterpret_cast<float4*>(sMin)[t] =
        reinterpret_cast<const float4*>(mean1f + (size_t)blk * 16 * HID)[t];
    {
        const uint2 hu = reinterpret_cast<const uint2*>(hb)[(size_t)blk * 256 + t];
        sHin[4 * t]     = bflo(hu.x);
        sHin[4 * t + 1] = bfhi(hu.x);
        sHin[4 * t + 2] = bflo(hu.y);
        sHin[4 * t + 3] = bfhi(hu.y);
    }
    __syncthreads();

    const int n = t >> 4, cg = t & 15;
    const float4 bv = reinterpret_cast<const float4*>(b1)[cg];
    float a[4] = {bv.x, bv.y, bv.z, bv.w};
#pragma unroll
    for (int k = 0; k < HID; ++k) {
        const float m  = sMin[n * HID + k];
        const float hh = sHin[n * HID + k];
        const float4 wl = reinterpret_cast<const float4*>(sWl + k * HID)[cg];
        const float4 wr = reinterpret_cast<const float4*>(sWr + k * HID)[cg];
        a[0] = fmaf(m, wl.x, fmaf(hh, wr.x, a[0]));
        a[1] = fmaf(m, wl.y, fmaf(hh, wr.y, a[1]));
        a[2] = fmaf(m, wl.z, fmaf(hh, wr.z, a[2]));
        a[3] = fmaf(m, wl.w, fmaf(hh, wr.w, a[3]));
    }
    float ss = a[0] * a[0] + a[1] * a[1] + a[2] * a[2] + a[3] * a[3];
    ss += __shfl_xor(ss, 1);
    ss += __shfl_xor(ss, 2);
    ss += __shfl_xor(ss, 4);
    ss += __shfl_xor(ss, 8);
    const float sc = 1.0f / fmaxf(sqrtf(ss), 1e-12f);
    sV[n * HID + 4 * cg + 0] = a[0] * sc;
    sV[n * HID + 4 * cg + 1] = a[1] * sc;
    sV[n * HID + 4 * cg + 2] = a[2] * sc;
    sV[n * HID + 4 * cg + 3] = a[3] * sc;
    __syncthreads();

    float c1a = bc1[cg], c1b = bc1[cg + 16];
#pragma unroll
    for (int k = 0; k < HID; ++k) {
        const float vv = sV[n * HID + k];
        c1a = fmaf(vv, sWc[k * 32 + cg], c1a);
        c1b = fmaf(vv, sWc[k * 32 + cg + 16], c1b);
    }
    float pp = fmaxf(c1a, 0.f) * Wc2[cg] + fmaxf(c1b, 0.f) * Wc2[cg + 16];
    pp += __shfl_xor(pp, 1);
    pp += __shfl_xor(pp, 2);
    pp += __shfl_xor(pp, 4);
    pp += __shfl_xor(pp, 8);
    if (cg == 0) out[blk * 16 + n] = pp + bc2[0];
}

extern "C" void kernel_launch(void* const* d_in, const int* in_sizes, int n_in,
                              void* d_out, int out_size, void* d_ws, size_t ws_size,
                              hipStream_t stream) {
    const float* x   = (const float*)d_in[0];
    const int*   ei  = (const int*)d_in[1];
    const float* Wl0 = (const float*)d_in[2];
    const float* b0  = (const float*)d_in[3];
    const float* Wr0 = (const float*)d_in[4];
    const float* Wl1 = (const float*)d_in[5];
    const float* b1  = (const float*)d_in[6];
    const float* Wr1 = (const float*)d_in[7];
    const float* Wc1 = (const float*)d_in[8];
    const float* bc1 = (const float*)d_in[9];
    const float* Wc2 = (const float*)d_in[10];
    const float* bc2 = (const float*)d_in[11];
    float* out = (float*)d_out;

    // ws layout (float offsets), liveness-packed, total 25.8 MB:
    //  region A [0, 3,200,000): part/btot/bstart (dead after sortW),
    //    bentry at [1,600,000,..) (dead after sortW), then mean0b [0,800,000)
    //    (dead after transform0), finally mean1f = whole A (written by agg1).
    float* W = (float*)d_ws;
    int*            part   = (int*)W;                         // 200,064 ints
    int*            btot   = (int*)(W + 200064);              // 1563
    int*            bstart = (int*)(W + 201632);              // 1564
    unsigned*       bentry = (unsigned*)(W + 1600000);        // 1.6M
    unsigned short* mean0b = (unsigned short*)W;              // N*32 bf16
    float*          mean1f = W;                               // N*64 f32
    int*            sorted_src = (int*)(W + 3200000);         // 1.6M
    int*            off    = (int*)(W + 4800000);             // 50,001
    unsigned short* hb     = (unsigned short*)(W + 4850016);  // N*64 bf16

    const int T = 256;
    histB_kernel<<<NB_BLD, T, 0, stream>>>(ei, part);
    scanA_kernel<<<NBUCK, NB_BLD, 0, stream>>>(part, btot);
    scanB_kernel<<<1, 1024, 0, stream>>>(btot, bstart);
    scatterB_kernel<<<NB_BLD, T, 0, stream>>>(ei, part, bstart, bentry);
    sortW_kernel<<<NBUCK, T, 0, stream>>>(bentry, bstart, sorted_src, off);

    const int ngrid = (N_NODES + 3) / 4;
    agg0_kernel<<<ngrid, T, 0, stream>>>(x, off, sorted_src, mean0b);
    transform0_kernel<<<NTB, T, 0, stream>>>(x, mean0b, Wl0, Wr0, b0, hb);
    agg1_kernel<<<ngrid, T, 0, stream>>>(hb, off, sorted_src, mean1f);
    transform1_kernel<<<NTB, T, 0, stream>>>(hb, mean1f, Wl1, Wr1, b1,
                                             Wc1, bc1, Wc2, bc2, out);
}